// Round 6
// baseline (313.757 us; speedup 1.0000x reference)
//
#include <hip/hip_runtime.h>

typedef unsigned short u16;
typedef unsigned int u32;
typedef __bf16 bf16x8 __attribute__((ext_vector_type(8)));
typedef short s16x4 __attribute__((ext_vector_type(4)));
typedef float f32x4 __attribute__((ext_vector_type(4)));

#define AS1(p) ((const __attribute__((address_space(1))) void*)(p))
#define AS3(p) ((__attribute__((address_space(3))) void*)(p))

#if __has_builtin(__builtin_amdgcn_exp2f)
#define EXP2(x) __builtin_amdgcn_exp2f(x)
#else
#define EXP2(x) __builtin_exp2f(x)
#endif

__device__ __forceinline__ u16 f2bf(float f) {
    u32 u = __float_as_uint(f);
    u += 0x7fffu + ((u >> 16) & 1u);   // round-to-nearest-even
    return (u16)(u >> 16);
}

__device__ __forceinline__ short bfbits(float f) {
    __bf16 h = (__bf16)f;
    return __builtin_bit_cast(short, h);
}

// Q/K/V/O buffers are each 24*4096*64 = 6291456 elements
#define NXQ 6291456
// Q scale: 1/sqrt(64) * log2(e), folded into Q projection so flash uses exp2
#define QSCALE 0.1803368801111249f

// ---------------- prep: 4x W transpose (fp32->bf16) + bias fuse ----------------
// 576 blocks: 4 mats x 144 tiles of 64x64
__global__ __launch_bounds__(256) void prep_kernel(
    const float* __restrict__ wq, const float* __restrict__ wk,
    const float* __restrict__ wv, const float* __restrict__ wo,
    const float* __restrict__ bq, const float* __restrict__ bk,
    const float* __restrict__ bv,
    u16* __restrict__ WT, float* __restrict__ bqkv)
{
    const int t = threadIdx.x;
    const int tb = blockIdx.x;            // 0..575
    int mat = tb / 144;
    int tt = tb - mat * 144;
    int tr = tt / 12, tc = tt - tr * 12;
    const float* W = (mat == 0) ? wq : (mat == 1) ? wk : (mat == 2) ? wv : wo;
    __shared__ u16 sT[64 * 72];
    #pragma unroll
    for (int rr = 0; rr < 4; ++rr) {
        int r = (t >> 4) + rr * 16;
        int cb = (t & 15) * 4;
        float4 v = *(const float4*)&W[(size_t)(tr * 64 + r) * 768 + tc * 64 + cb];
        sT[(cb + 0) * 72 + r] = f2bf(v.x);
        sT[(cb + 1) * 72 + r] = f2bf(v.y);
        sT[(cb + 2) * 72 + r] = f2bf(v.z);
        sT[(cb + 3) * 72 + r] = f2bf(v.w);
    }
    __syncthreads();
    #pragma unroll
    for (int i = 0; i < 2; ++i) {
        int nr = t >> 2;
        int cc = (t & 3) * 16 + i * 8;
        *(uint4*)&WT[(size_t)(mat * 768 + tc * 64 + nr) * 768 + tr * 64 + cc] =
            *(uint4*)&sT[nr * 72 + cc];
    }
    if (tb < 9) {
        int i = tb * 256 + t;
        if (i < 2304)
            bqkv[i] = (i < 768) ? bq[i] : (i < 1536) ? bk[i - 768] : bv[i - 1536];
    }
}

// ---------------- QKV GEMM: fp32 A inline-cast, BK=32 dbuf, LDS-transpose epilogue --
// A = x fp32 [8192][768]; WT rows 0..2303 bf16. mat = blockIdx.y/6:
//   0 -> Q [bh][s][d] scaled by QSCALE; 1 -> K [bh][s][d]; 2 -> V^T [bh][d][s]
__global__ __launch_bounds__(256, 4) void gemm_qkv(
    const float* __restrict__ X, const u16* __restrict__ WT,
    const float* __restrict__ bias, u16* __restrict__ out)
{
    __shared__ u16 sh[16384];   // [0:8192) = sA[2][4096], [8192:16384) = sB[2][4096]
                                // epilogue reuses all 32 KB as a 128x128 bf16 tile
    const int m0 = blockIdx.x * 128;
    const int n0g = blockIdx.y * 128;
    const int tid = threadIdx.x, lane = tid & 63, wave = tid >> 6;
    const int quad = lane >> 4, l16 = lane & 15;
    const int wm = (wave & 1) * 64, wn = (wave >> 1) * 64;

    f32x4 acc[4][4];
    #pragma unroll
    for (int i = 0; i < 4; ++i)
        #pragma unroll
        for (int j = 0; j < 4; ++j)
            #pragma unroll
            for (int r = 0; r < 4; ++r)
                acc[i][j][r] = 0.f;

    const int srow = lane >> 2;          // row within 16-row chunk
    const int scc = lane & 3;            // k-chunk (8 elements)

    // A: load 8 fp32, cvt, ds_write_b128 (same swizzled slot the DMA would fill)
    auto stageA = [&](int k0, int buf) {
        #pragma unroll
        for (int i = 0; i < 2; ++i) {
            int c = wave * 2 + i;
            int row = c * 16 + srow;
            int kc = (scc ^ (row & 3)) * 8;
            const float* src = &X[(size_t)(m0 + row) * 768 + k0 + kc];
            float4 v0 = *(const float4*)src;
            float4 v1 = *(const float4*)(src + 4);
            uint4 o;
            o.x = (u32)f2bf(v0.x) | ((u32)f2bf(v0.y) << 16);
            o.y = (u32)f2bf(v0.z) | ((u32)f2bf(v0.w) << 16);
            o.z = (u32)f2bf(v1.x) | ((u32)f2bf(v1.y) << 16);
            o.w = (u32)f2bf(v1.z) | ((u32)f2bf(v1.w) << 16);
            *(uint4*)&sh[buf * 4096 + c * 512 + lane * 8] = o;
        }
    };
    auto stageB = [&](int k0, int buf) {
        #pragma unroll
        for (int i = 0; i < 2; ++i) {
            int c = wave * 2 + i;
            int row = c * 16 + srow;
            int kc = (scc ^ (row & 3)) * 8;
            __builtin_amdgcn_global_load_lds(
                AS1(&WT[(size_t)(n0g + row) * 768 + k0 + kc]),
                AS3(&sh[8192 + buf * 4096 + c * 512]), 16, 0, 0);
        }
    };

    auto compute = [&](int buf) {
        bf16x8 af[4], bfr[4];
        #pragma unroll
        for (int i = 0; i < 4; ++i) {
            int row = wm + i * 16 + l16;
            af[i] = *(const bf16x8*)&sh[buf * 4096 + row * 32 + ((quad ^ (row & 3)) * 8)];
        }
        #pragma unroll
        for (int j = 0; j < 4; ++j) {
            int row = wn + j * 16 + l16;
            bfr[j] = *(const bf16x8*)&sh[8192 + buf * 4096 + row * 32 + ((quad ^ (row & 3)) * 8)];
        }
        #pragma unroll
        for (int i = 0; i < 4; ++i)
            #pragma unroll
            for (int j = 0; j < 4; ++j)
                acc[i][j] = __builtin_amdgcn_mfma_f32_16x16x32_bf16(af[i], bfr[j], acc[i][j], 0, 0, 0);
    };

    stageB(0, 0); stageA(0, 0);
    for (int kt = 0; kt < 24; kt += 2) {
        __syncthreads();
        stageB((kt + 1) * 32, 1); stageA((kt + 1) * 32, 1);
        compute(0);
        __syncthreads();
        if (kt + 2 < 24) { stageB((kt + 2) * 32, 0); stageA((kt + 2) * 32, 0); }
        compute(1);
    }

    // ---- epilogue: acc -> LDS (bf16, mat-dependent orientation) -> coalesced stores
    __syncthreads();
    const int mat = blockIdx.y / 6;
    const int nm0 = n0g - mat * 768;
    const float scale = (mat == 0) ? QSCALE : 1.0f;
    #pragma unroll
    for (int i = 0; i < 4; ++i) {
        #pragma unroll
        for (int j = 0; j < 4; ++j) {
            int col = wn + j * 16 + l16;           // n-local
            float bv = bias[n0g + col];
            #pragma unroll
            for (int r = 0; r < 4; ++r) {
                int row = wm + i * 16 + quad * 4 + r;   // m-local
                u16 v = f2bf((acc[i][j][r] + bv) * scale);
                if (mat < 2) sh[row * 128 + col] = v;   // [s][n]
                else         sh[col * 128 + row] = v;   // [d][s]
            }
        }
    }
    __syncthreads();
    const int r0 = tid >> 1, half = tid & 1;
    u16* dst = out + (size_t)mat * NXQ;
    u16* p;
    if (mat < 2) {
        int gs = m0 + r0;
        int b = gs >> 12, s = gs & 4095;
        int h = (nm0 + half * 64) >> 6;
        p = &dst[(((size_t)(b * 12 + h) * 4096) + s) * 64];
    } else {
        int gd = nm0 + r0;
        int h = gd >> 6, d = gd & 63;
        int s0 = m0 + half * 64;
        int b = s0 >> 12, s = s0 & 4095;
        p = &dst[(((size_t)(b * 12 + h) * 64 + d) * 4096) + s];
    }
    #pragma unroll
    for (int q = 0; q < 8; ++q)
        *(uint4*)&p[q * 8] = *(uint4*)&sh[r0 * 128 + half * 64 + q * 8];
}

// ---------------- out-proj GEMM: 64x128 tile, BK=32 dbuf, grid 768 ----------------
__global__ __launch_bounds__(256, 4) void gemm_out(
    const u16* __restrict__ A, const u16* __restrict__ WT,
    const float* __restrict__ bias, float* __restrict__ out)
{
    __shared__ u16 sA[2][64 * 32];
    __shared__ u16 sB[2][128 * 32];
    const int m0 = blockIdx.x * 64;
    const int n0 = blockIdx.y * 128;
    const int tid = threadIdx.x, lane = tid & 63, wave = tid >> 6;
    const int quad = lane >> 4, l16 = lane & 15;
    const int wm = (wave & 1) * 32, wn = (wave >> 1) * 64;

    f32x4 acc[2][4];
    #pragma unroll
    for (int i = 0; i < 2; ++i)
        #pragma unroll
        for (int j = 0; j < 4; ++j)
            #pragma unroll
            for (int r = 0; r < 4; ++r)
                acc[i][j][r] = 0.f;

    const int srow = lane >> 2;
    const int scc = lane & 3;

    auto stage = [&](int k0, int buf) {
        {
            int row = wave * 16 + srow;
            int kc = (scc ^ (row & 3)) * 8;
            __builtin_amdgcn_global_load_lds(
                AS1(&A[(size_t)(m0 + row) * 768 + k0 + kc]),
                AS3(&sA[buf][wave * 512]), 16, 0, 0);
        }
        #pragma unroll
        for (int i = 0; i < 2; ++i) {
            int c = wave * 2 + i;
            int row = c * 16 + srow;
            int kc = (scc ^ (row & 3)) * 8;
            __builtin_amdgcn_global_load_lds(
                AS1(&WT[(size_t)(n0 + row) * 768 + k0 + kc]),
                AS3(&sB[buf][c * 512]), 16, 0, 0);
        }
    };

    auto compute = [&](int buf) {
        bf16x8 af[2], bfr[4];
        #pragma unroll
        for (int i = 0; i < 2; ++i) {
            int row = wm + i * 16 + l16;
            af[i] = *(const bf16x8*)&sA[buf][row * 32 + ((quad ^ (row & 3)) * 8)];
        }
        #pragma unroll
        for (int j = 0; j < 4; ++j) {
            int row = wn + j * 16 + l16;
            bfr[j] = *(const bf16x8*)&sB[buf][row * 32 + ((quad ^ (row & 3)) * 8)];
        }
        #pragma unroll
        for (int i = 0; i < 2; ++i)
            #pragma unroll
            for (int j = 0; j < 4; ++j)
                acc[i][j] = __builtin_amdgcn_mfma_f32_16x16x32_bf16(af[i], bfr[j], acc[i][j], 0, 0, 0);
    };

    stage(0, 0);
    for (int kt = 0; kt < 24; kt += 2) {
        __syncthreads();
        stage((kt + 1) * 32, 1);
        compute(0);
        __syncthreads();
        if (kt + 2 < 24) stage((kt + 2) * 32, 0);
        compute(1);
    }

    #pragma unroll
    for (int i = 0; i < 2; ++i) {
        #pragma unroll
        for (int j = 0; j < 4; ++j) {
            int col = n0 + wn + j * 16 + l16;
            float bv = bias[col];
            #pragma unroll
            for (int r = 0; r < 4; ++r) {
                int row = m0 + wm + i * 16 + quad * 4 + r;
                out[(size_t)row * 768 + col] = acc[i][j][r] + bv;
            }
        }
    }
}

// ---------------- flash attention (round-4 config: 128 q rows, 3 blocks/CU) -------
// Q pre-scaled by QSCALE -> p = exp2(score). Row-sums l via all-ones MFMA A-frag.
__global__ __launch_bounds__(256, 2) void flash_kernel(
    const u16* __restrict__ Q, const u16* __restrict__ K,
    const u16* __restrict__ Vt, u16* __restrict__ O)
{
    const int bh = blockIdx.y;
    const int q0 = blockIdx.x * 128;
    const u16* Qp = Q + (size_t)bh * 4096 * 64;
    const u16* Kp = K + (size_t)bh * 4096 * 64;
    const u16* Vp = Vt + (size_t)bh * 64 * 4096;
    const int tid = threadIdx.x, lane = tid & 63, wave = tid >> 6;
    const int quad = lane >> 4, l16 = lane & 15;

    __shared__ u16 sK[2][64 * 64];    // [key][d], XOR-swizzled chunks
    __shared__ u16 sVT[2][64 * 64];   // [d][key]

    const int qrow = q0 + wave * 32;
    bf16x8 qf[2][2];
    #pragma unroll
    for (int i = 0; i < 2; ++i)
        #pragma unroll
        for (int s = 0; s < 2; ++s)
            qf[i][s] = *(const bf16x8*)&Qp[(size_t)(qrow + i * 16 + l16) * 64 + s * 32 + quad * 8];

    f32x4 oacc[4][2];
    f32x4 lacc[2];
    #pragma unroll
    for (int jd = 0; jd < 4; ++jd)
        #pragma unroll
        for (int i = 0; i < 2; ++i)
            #pragma unroll
            for (int r = 0; r < 4; ++r)
                oacc[jd][i][r] = 0.f;
    #pragma unroll
    for (int i = 0; i < 2; ++i)
        #pragma unroll
        for (int r = 0; r < 4; ++r)
            lacc[i][r] = 0.f;

    s16x4 ones;   // bf16 1.0 x4 : all-ones 16x16 A-operand (lane-invariant)
    #pragma unroll
    for (int r = 0; r < 4; ++r) ones[r] = (short)0x3F80;

    const int srow = lane >> 3;
    auto stage = [&](int t, int buf) {
        #pragma unroll
        for (int i = 0; i < 2; ++i) {
            int c = wave * 2 + i;
            int row = c * 8 + srow;
            int kc = ((lane & 7) ^ (row & 7)) * 8;
            __builtin_amdgcn_global_load_lds(
                AS1(&Kp[(size_t)(t * 64 + row) * 64 + kc]),
                AS3(&sK[buf][c * 512]), 16, 0, 0);
            __builtin_amdgcn_global_load_lds(
                AS1(&Vp[(size_t)row * 4096 + t * 64 + kc]),
                AS3(&sVT[buf][c * 512]), 16, 0, 0);
        }
    };

    auto body = [&](int cur) {
        f32x4 sacc[4][2];
        #pragma unroll
        for (int m = 0; m < 4; ++m)
            #pragma unroll
            for (int i = 0; i < 2; ++i)
                #pragma unroll
                for (int r = 0; r < 4; ++r)
                    sacc[m][i][r] = 0.f;
        #pragma unroll
        for (int s = 0; s < 2; ++s) {
            bf16x8 ak[4];
            #pragma unroll
            for (int m = 0; m < 4; ++m) {
                int row = m * 16 + l16;
                ak[m] = *(const bf16x8*)&sK[cur][row * 64 + (((s * 4 + quad) ^ (row & 7)) * 8)];
            }
            #pragma unroll
            for (int m = 0; m < 4; ++m)
                #pragma unroll
                for (int i = 0; i < 2; ++i)
                    sacc[m][i] = __builtin_amdgcn_mfma_f32_16x16x32_bf16(ak[m], qf[i][s], sacc[m][i], 0, 0, 0);
        }

        s16x4 bp[4][2];
        #pragma unroll
        for (int i = 0; i < 2; ++i) {
            #pragma unroll
            for (int kk = 0; kk < 4; ++kk) {
                s16x4 b;
                b[0] = bfbits(EXP2(sacc[kk][i][0]));
                b[1] = bfbits(EXP2(sacc[kk][i][1]));
                b[2] = bfbits(EXP2(sacc[kk][i][2]));
                b[3] = bfbits(EXP2(sacc[kk][i][3]));
                bp[kk][i] = b;
            }
        }

        #pragma unroll
        for (int kk = 0; kk < 4; ++kk) {
            s16x4 av[4];
            #pragma unroll
            for (int jd = 0; jd < 4; ++jd) {
                int row = jd * 16 + l16;
                av[jd] = *(const s16x4*)&sVT[cur][row * 64 +
                            (((kk * 2 + (quad >> 1)) ^ (row & 7)) * 8) + (quad & 1) * 4];
            }
            #pragma unroll
            for (int i = 0; i < 2; ++i) {
                #pragma unroll
                for (int jd = 0; jd < 4; ++jd)
                    oacc[jd][i] = __builtin_amdgcn_mfma_f32_16x16x16bf16_1k(av[jd], bp[kk][i], oacc[jd][i], 0, 0, 0);
                lacc[i] = __builtin_amdgcn_mfma_f32_16x16x16bf16_1k(ones, bp[kk][i], lacc[i], 0, 0, 0);
            }
        }
    };

    stage(0, 0);
    for (int t = 0; t < 64; t += 2) {
        __syncthreads();
        stage(t + 1, 1);
        body(0);
        __syncthreads();
        if (t + 2 < 64) stage(t + 2, 0);
        body(1);
    }

    const int b = bh / 12, h = bh - b * 12;
    #pragma unroll
    for (int i = 0; i < 2; ++i) {
        float inv = 1.0f / lacc[i][0];
        int s = qrow + i * 16 + l16;
        #pragma unroll
        for (int jd = 0; jd < 4; ++jd) {
            ushort4 w;
            w.x = f2bf(oacc[jd][i][0] * inv);
            w.y = f2bf(oacc[jd][i][1] * inv);
            w.z = f2bf(oacc[jd][i][2] * inv);
            w.w = f2bf(oacc[jd][i][3] * inv);
            *(ushort4*)&O[((size_t)(b * 4096 + s)) * 768 + h * 64 + jd * 16 + quad * 4] = w;
        }
    }
}

extern "C" void kernel_launch(void* const* d_in, const int* in_sizes, int n_in,
                              void* d_out, int out_size, void* d_ws, size_t ws_size,
                              hipStream_t stream)
{
    (void)in_sizes; (void)n_in; (void)out_size; (void)ws_size;
    const float* x  = (const float*)d_in[0];
    const float* wq = (const float*)d_in[1];
    const float* bq = (const float*)d_in[2];
    const float* wk = (const float*)d_in[3];
    const float* bk = (const float*)d_in[4];
    const float* wv = (const float*)d_in[5];
    const float* bv = (const float*)d_in[6];
    const float* wo = (const float*)d_in[7];
    const float* bo = (const float*)d_in[8];
    float* out = (float*)d_out;

    u16* ws = (u16*)d_ws;
    u16* WT  = ws;                          // 3072*768 (WqT|WkT|WvT|WoT)
    u16* Qb  = WT + (size_t)3072 * 768;     // NXQ each
    u16* Kb  = Qb + NXQ;
    u16* Vtb = Kb + NXQ;
    u16* Ob  = Vtb + NXQ;
    float* bqkv = (float*)(Ob + NXQ);       // 2304 fp32

    prep_kernel<<<576, 256, 0, stream>>>(wq, wk, wv, wo, bq, bk, bv, WT, bqkv);
    gemm_qkv<<<dim3(64, 18), 256, 0, stream>>>(x, WT, bqkv, Qb);
    flash_kernel<<<dim3(32, 24), 256, 0, stream>>>(Qb, Kb, Vtb, Ob);
    gemm_out<<<dim3(128, 6), 256, 0, stream>>>(Ob, WT + (size_t)2304 * 768, bo, out);
}

// Round 7
// 275.943 us; speedup vs baseline: 1.1370x; 1.1370x over previous
//
#include <hip/hip_runtime.h>

typedef unsigned short u16;
typedef unsigned int u32;
typedef __bf16 bf16x8 __attribute__((ext_vector_type(8)));
typedef short s16x4 __attribute__((ext_vector_type(4)));
typedef float f32x4 __attribute__((ext_vector_type(4)));

#define AS1(p) ((const __attribute__((address_space(1))) void*)(p))
#define AS3(p) ((__attribute__((address_space(3))) void*)(p))

#if __has_builtin(__builtin_amdgcn_exp2f)
#define EXP2(x) __builtin_amdgcn_exp2f(x)
#else
#define EXP2(x) __builtin_exp2f(x)
#endif

__device__ __forceinline__ u16 f2bf(float f) {
    u32 u = __float_as_uint(f);
    u += 0x7fffu + ((u >> 16) & 1u);   // round-to-nearest-even
    return (u16)(u >> 16);
}

__device__ __forceinline__ short bfbits(float f) {
    __bf16 h = (__bf16)f;
    return __builtin_bit_cast(short, h);
}

// Q/K/V/O buffers are each 24*4096*64 = 6291456 elements
#define NXQ 6291456
// Q scale: 1/sqrt(64) * log2(e), folded into Q projection so flash uses exp2
#define QSCALE 0.1803368801111249f

// ---------------- prep: x cast + 4x W transpose (bf16) + bias fuse ----------------
// grid: 6144 blocks (x cast) + 576 blocks (transpose: 4 mats x 12x12 tiles of 64x64)
__global__ __launch_bounds__(256) void prep_kernel(
    const float* __restrict__ x,
    const float* __restrict__ wq, const float* __restrict__ wk,
    const float* __restrict__ wv, const float* __restrict__ wo,
    const float* __restrict__ bq, const float* __restrict__ bk,
    const float* __restrict__ bv,
    u16* __restrict__ xbf, u16* __restrict__ WT, float* __restrict__ bqkv)
{
    const int t = threadIdx.x;
    const int bid = blockIdx.x;
    if (bid < 6144) {                     // x: 8192*768 fp32 -> bf16
        int i = bid * 256 + t;
        float4 v = ((const float4*)x)[i];
        uint2 o;
        o.x = (u32)f2bf(v.x) | ((u32)f2bf(v.y) << 16);
        o.y = (u32)f2bf(v.z) | ((u32)f2bf(v.w) << 16);
        ((uint2*)xbf)[i] = o;
        return;
    }
    int tb = bid - 6144;                  // 0..575
    int mat = tb / 144;
    int tt = tb - mat * 144;
    int tr = tt / 12, tc = tt - tr * 12;
    const float* W = (mat == 0) ? wq : (mat == 1) ? wk : (mat == 2) ? wv : wo;
    __shared__ u16 sT[64 * 72];
    #pragma unroll
    for (int rr = 0; rr < 4; ++rr) {
        int r = (t >> 4) + rr * 16;
        int cb = (t & 15) * 4;
        float4 v = *(const float4*)&W[(size_t)(tr * 64 + r) * 768 + tc * 64 + cb];
        sT[(cb + 0) * 72 + r] = f2bf(v.x);
        sT[(cb + 1) * 72 + r] = f2bf(v.y);
        sT[(cb + 2) * 72 + r] = f2bf(v.z);
        sT[(cb + 3) * 72 + r] = f2bf(v.w);
    }
    __syncthreads();
    #pragma unroll
    for (int i = 0; i < 2; ++i) {
        int nr = t >> 2;
        int cc = (t & 3) * 16 + i * 8;
        *(uint4*)&WT[(size_t)(mat * 768 + tc * 64 + nr) * 768 + tr * 64 + cc] =
            *(uint4*)&sT[nr * 72 + cc];
    }
    if (tb < 9) {
        int i = tb * 256 + t;
        if (i < 2304)
            bqkv[i] = (i < 768) ? bq[i] : (i < 1536) ? bk[i - 768] : bv[i - 1536];
    }
}

// ---------------- GEMM: BK=64 single-buffer, global_load_lds + XOR swizzle --------
// MODE 0: QKV fused. A=xbf[8192][768], WT rows 0..2303, out base = Qb (Kb,Vtb follow).
//         mat = blockIdx.y/6: 0->Q (scale QSCALE, [bh][s][d]), 1->K, 2->V^T [bh][d][s]
// MODE 1: out-proj. A=Ob[8192][768] bf16, WT=WoT, out fp32 [8192][768] + bias.
template<int MODE>
__global__ __launch_bounds__(256, 4) void gemm_kernel(
    const u16* __restrict__ A, const u16* __restrict__ WT,
    const float* __restrict__ bias, void* __restrict__ out)
{
    __shared__ u16 sA[128 * 64];   // swizzled: [row][cc*8+j] = A[m0+row][k0+(cc^(row&7))*8+j]
    __shared__ u16 sB[128 * 64];

    const int m0 = blockIdx.x * 128;
    const int n0g = blockIdx.y * 128;
    const int tid = threadIdx.x, lane = tid & 63, wave = tid >> 6;
    const int quad = lane >> 4, l16 = lane & 15;
    const int wm = (wave & 1) * 64, wn = (wave >> 1) * 64;

    f32x4 acc[4][4];
    #pragma unroll
    for (int i = 0; i < 4; ++i)
        #pragma unroll
        for (int j = 0; j < 4; ++j)
            #pragma unroll
            for (int r = 0; r < 4; ++r)
                acc[i][j][r] = 0.f;

    const int srow = (lane >> 3);           // row within 8-row chunk

    for (int k0 = 0; k0 < 768; k0 += 64) {
        __syncthreads();
        #pragma unroll
        for (int i = 0; i < 4; ++i) {
            int c = wave * 4 + i;           // chunk: rows 8c..8c+7
            int row = c * 8 + srow;
            __builtin_amdgcn_global_load_lds(
                AS1(&A[(size_t)(m0 + row) * 768 + k0 + (((lane & 7) ^ (row & 7)) * 8)]),
                AS3(&sA[c * 512]), 16, 0, 0);
            __builtin_amdgcn_global_load_lds(
                AS1(&WT[(size_t)(n0g + row) * 768 + k0 + (((lane & 7) ^ (row & 7)) * 8)]),
                AS3(&sB[c * 512]), 16, 0, 0);
        }
        __syncthreads();
        #pragma unroll
        for (int s = 0; s < 2; ++s) {
            bf16x8 af[4], bfr[4];
            #pragma unroll
            for (int i = 0; i < 4; ++i) {
                int row = wm + i * 16 + l16;
                af[i] = *(const bf16x8*)&sA[row * 64 + (((s * 4 + quad) ^ (row & 7)) * 8)];
            }
            #pragma unroll
            for (int j = 0; j < 4; ++j) {
                int row = wn + j * 16 + l16;
                bfr[j] = *(const bf16x8*)&sB[row * 64 + (((s * 4 + quad) ^ (row & 7)) * 8)];
            }
            #pragma unroll
            for (int i = 0; i < 4; ++i)
                #pragma unroll
                for (int j = 0; j < 4; ++j)
                    acc[i][j] = __builtin_amdgcn_mfma_f32_16x16x32_bf16(af[i], bfr[j], acc[i][j], 0, 0, 0);
        }
    }

    // epilogue: C/D layout col=l16, row=quad*4+r
    if (MODE == 0) {
        const int mat = blockIdx.y / 6;
        const int nm0 = n0g - mat * 768;
        const float scale = (mat == 0) ? QSCALE : 1.0f;
        u16* dst = (u16*)out + (size_t)mat * NXQ;
        #pragma unroll
        for (int i = 0; i < 4; ++i) {
            #pragma unroll
            for (int j = 0; j < 4; ++j) {
                int colg = n0g + wn + j * 16 + l16;
                int col = nm0 + wn + j * 16 + l16;
                float bv = bias[colg];
                int h = col >> 6, d = col & 63;
                int row0 = m0 + wm + i * 16 + quad * 4;
                int b = row0 >> 12, s = row0 & 4095;
                if (mat < 2) {
                    #pragma unroll
                    for (int r = 0; r < 4; ++r)
                        dst[(((size_t)(b * 12 + h) * 4096) + s + r) * 64 + d] =
                            f2bf((acc[i][j][r] + bv) * scale);
                } else {
                    ushort4 w;
                    w.x = f2bf(acc[i][j][0] + bv);
                    w.y = f2bf(acc[i][j][1] + bv);
                    w.z = f2bf(acc[i][j][2] + bv);
                    w.w = f2bf(acc[i][j][3] + bv);
                    *(ushort4*)&dst[(((size_t)(b * 12 + h) * 64 + d) * 4096) + s] = w;
                }
            }
        }
    } else {
        #pragma unroll
        for (int i = 0; i < 4; ++i) {
            #pragma unroll
            for (int j = 0; j < 4; ++j) {
                int col = n0g + wn + j * 16 + l16;
                float bv = bias[col];
                #pragma unroll
                for (int r = 0; r < 4; ++r) {
                    int row = m0 + wm + i * 16 + quad * 4 + r;
                    ((float*)out)[(size_t)row * 768 + col] = acc[i][j][r] + bv;
                }
            }
        }
    }
}

// ---------------- flash attention (R4 config: 128 q rows, dbuf DMA staging) -------
// Q pre-scaled by QSCALE -> p = exp2(score). Row-sums l via all-ones MFMA A-frag.
__global__ __launch_bounds__(256, 2) void flash_kernel(
    const u16* __restrict__ Q, const u16* __restrict__ K,
    const u16* __restrict__ Vt, u16* __restrict__ O)
{
    const int bh = blockIdx.y;
    const int q0 = blockIdx.x * 128;
    const u16* Qp = Q + (size_t)bh * 4096 * 64;
    const u16* Kp = K + (size_t)bh * 4096 * 64;
    const u16* Vp = Vt + (size_t)bh * 64 * 4096;
    const int tid = threadIdx.x, lane = tid & 63, wave = tid >> 6;
    const int quad = lane >> 4, l16 = lane & 15;

    __shared__ u16 sK[2][64 * 64];    // [key][d], XOR-swizzled chunks
    __shared__ u16 sVT[2][64 * 64];   // [d][key]

    const int qrow = q0 + wave * 32;
    bf16x8 qf[2][2];
    #pragma unroll
    for (int i = 0; i < 2; ++i)
        #pragma unroll
        for (int s = 0; s < 2; ++s)
            qf[i][s] = *(const bf16x8*)&Qp[(size_t)(qrow + i * 16 + l16) * 64 + s * 32 + quad * 8];

    f32x4 oacc[4][2];
    f32x4 lacc[2];
    #pragma unroll
    for (int jd = 0; jd < 4; ++jd)
        #pragma unroll
        for (int i = 0; i < 2; ++i)
            #pragma unroll
            for (int r = 0; r < 4; ++r)
                oacc[jd][i][r] = 0.f;
    #pragma unroll
    for (int i = 0; i < 2; ++i)
        #pragma unroll
        for (int r = 0; r < 4; ++r)
            lacc[i][r] = 0.f;

    s16x4 ones;   // bf16 1.0 x4 : all-ones 16x16 A-operand (lane-invariant)
    #pragma unroll
    for (int r = 0; r < 4; ++r) ones[r] = (short)0x3F80;

    const int srow = lane >> 3;
    auto stage = [&](int t, int buf) {
        #pragma unroll
        for (int i = 0; i < 2; ++i) {
            int c = wave * 2 + i;
            int row = c * 8 + srow;
            int kc = ((lane & 7) ^ (row & 7)) * 8;
            __builtin_amdgcn_global_load_lds(
                AS1(&Kp[(size_t)(t * 64 + row) * 64 + kc]),
                AS3(&sK[buf][c * 512]), 16, 0, 0);
            __builtin_amdgcn_global_load_lds(
                AS1(&Vp[(size_t)row * 4096 + t * 64 + kc]),
                AS3(&sVT[buf][c * 512]), 16, 0, 0);
        }
    };

    auto body = [&](int cur) {
        f32x4 sacc[4][2];
        #pragma unroll
        for (int m = 0; m < 4; ++m)
            #pragma unroll
            for (int i = 0; i < 2; ++i)
                #pragma unroll
                for (int r = 0; r < 4; ++r)
                    sacc[m][i][r] = 0.f;
        #pragma unroll
        for (int s = 0; s < 2; ++s) {
            bf16x8 ak[4];
            #pragma unroll
            for (int m = 0; m < 4; ++m) {
                int row = m * 16 + l16;
                ak[m] = *(const bf16x8*)&sK[cur][row * 64 + (((s * 4 + quad) ^ (row & 7)) * 8)];
            }
            #pragma unroll
            for (int m = 0; m < 4; ++m)
                #pragma unroll
                for (int i = 0; i < 2; ++i)
                    sacc[m][i] = __builtin_amdgcn_mfma_f32_16x16x32_bf16(ak[m], qf[i][s], sacc[m][i], 0, 0, 0);
        }

        s16x4 bp[4][2];
        #pragma unroll
        for (int i = 0; i < 2; ++i) {
            #pragma unroll
            for (int kk = 0; kk < 4; ++kk) {
                s16x4 b;
                b[0] = bfbits(EXP2(sacc[kk][i][0]));
                b[1] = bfbits(EXP2(sacc[kk][i][1]));
                b[2] = bfbits(EXP2(sacc[kk][i][2]));
                b[3] = bfbits(EXP2(sacc[kk][i][3]));
                bp[kk][i] = b;
            }
        }

        #pragma unroll
        for (int kk = 0; kk < 4; ++kk) {
            s16x4 av[4];
            #pragma unroll
            for (int jd = 0; jd < 4; ++jd) {
                int row = jd * 16 + l16;
                av[jd] = *(const s16x4*)&sVT[cur][row * 64 +
                            (((kk * 2 + (quad >> 1)) ^ (row & 7)) * 8) + (quad & 1) * 4];
            }
            #pragma unroll
            for (int i = 0; i < 2; ++i) {
                #pragma unroll
                for (int jd = 0; jd < 4; ++jd)
                    oacc[jd][i] = __builtin_amdgcn_mfma_f32_16x16x16bf16_1k(av[jd], bp[kk][i], oacc[jd][i], 0, 0, 0);
                lacc[i] = __builtin_amdgcn_mfma_f32_16x16x16bf16_1k(ones, bp[kk][i], lacc[i], 0, 0, 0);
            }
        }
    };

    stage(0, 0);
    for (int t = 0; t < 64; t += 2) {
        __syncthreads();
        stage(t + 1, 1);
        body(0);
        __syncthreads();
        if (t + 2 < 64) stage(t + 2, 0);
        body(1);
    }

    const int b = bh / 12, h = bh - b * 12;
    #pragma unroll
    for (int i = 0; i < 2; ++i) {
        float inv = 1.0f / lacc[i][0];
        int s = qrow + i * 16 + l16;
        #pragma unroll
        for (int jd = 0; jd < 4; ++jd) {
            ushort4 w;
            w.x = f2bf(oacc[jd][i][0] * inv);
            w.y = f2bf(oacc[jd][i][1] * inv);
            w.z = f2bf(oacc[jd][i][2] * inv);
            w.w = f2bf(oacc[jd][i][3] * inv);
            *(ushort4*)&O[((size_t)(b * 4096 + s)) * 768 + h * 64 + jd * 16 + quad * 4] = w;
        }
    }
}

extern "C" void kernel_launch(void* const* d_in, const int* in_sizes, int n_in,
                              void* d_out, int out_size, void* d_ws, size_t ws_size,
                              hipStream_t stream)
{
    (void)in_sizes; (void)n_in; (void)out_size; (void)ws_size;
    const float* x  = (const float*)d_in[0];
    const float* wq = (const float*)d_in[1];
    const float* bq = (const float*)d_in[2];
    const float* wk = (const float*)d_in[3];
    const float* bk = (const float*)d_in[4];
    const float* wv = (const float*)d_in[5];
    const float* bv = (const float*)d_in[6];
    const float* wo = (const float*)d_in[7];
    const float* bo = (const float*)d_in[8];
    float* out = (float*)d_out;

    u16* ws = (u16*)d_ws;
    u16* xbf = ws;                          // 8192*768
    u16* WT  = xbf + (size_t)8192 * 768;    // 3072*768 (WqT|WkT|WvT|WoT)
    u16* Qb  = WT + (size_t)3072 * 768;     // NXQ each
    u16* Kb  = Qb + NXQ;
    u16* Vtb = Kb + NXQ;
    u16* Ob  = Vtb + NXQ;
    float* bqkv = (float*)(Ob + NXQ);       // 2304 fp32

    prep_kernel<<<6720, 256, 0, stream>>>(x, wq, wk, wv, wo, bq, bk, bv, xbf, WT, bqkv);
    gemm_kernel<0><<<dim3(64, 18), 256, 0, stream>>>(xbf, WT, bqkv, Qb);
    flash_kernel<<<dim3(32, 24), 256, 0, stream>>>(Qb, Kb, Vtb, Ob);
    gemm_kernel<1><<<dim3(64, 6), 256, 0, stream>>>(Ob, WT + (size_t)2304 * 768, bo, out);
}

// Round 8
// 266.316 us; speedup vs baseline: 1.1781x; 1.0361x over previous
//
#include <hip/hip_runtime.h>

typedef unsigned short u16;
typedef unsigned int u32;
typedef __bf16 bf16x8 __attribute__((ext_vector_type(8)));
typedef short s16x4 __attribute__((ext_vector_type(4)));
typedef float f32x4 __attribute__((ext_vector_type(4)));

#define AS1(p) ((const __attribute__((address_space(1))) void*)(p))
#define AS3(p) ((__attribute__((address_space(3))) void*)(p))

#if __has_builtin(__builtin_amdgcn_exp2f)
#define EXP2(x) __builtin_amdgcn_exp2f(x)
#else
#define EXP2(x) __builtin_exp2f(x)
#endif

__device__ __forceinline__ u16 f2bf(float f) {
    u32 u = __float_as_uint(f);
    u += 0x7fffu + ((u >> 16) & 1u);   // round-to-nearest-even
    return (u16)(u >> 16);
}

__device__ __forceinline__ short bfbits(float f) {
    __bf16 h = (__bf16)f;
    return __builtin_bit_cast(short, h);
}

// Q/K/V/O buffers are each 24*4096*64 = 6291456 elements
#define NXQ 6291456
// Q scale: 1/sqrt(64) * log2(e), folded into Q projection so flash uses exp2
#define QSCALE 0.1803368801111249f

// ---------------- prep: x cast + 4x W transpose (bf16) + bias fuse ----------------
__global__ __launch_bounds__(256) void prep_kernel(
    const float* __restrict__ x,
    const float* __restrict__ wq, const float* __restrict__ wk,
    const float* __restrict__ wv, const float* __restrict__ wo,
    const float* __restrict__ bq, const float* __restrict__ bk,
    const float* __restrict__ bv,
    u16* __restrict__ xbf, u16* __restrict__ WT, float* __restrict__ bqkv)
{
    const int t = threadIdx.x;
    const int bid = blockIdx.x;
    if (bid < 6144) {                     // x: 8192*768 fp32 -> bf16
        int i = bid * 256 + t;
        float4 v = ((const float4*)x)[i];
        uint2 o;
        o.x = (u32)f2bf(v.x) | ((u32)f2bf(v.y) << 16);
        o.y = (u32)f2bf(v.z) | ((u32)f2bf(v.w) << 16);
        ((uint2*)xbf)[i] = o;
        return;
    }
    int tb = bid - 6144;                  // 0..575
    int mat = tb / 144;
    int tt = tb - mat * 144;
    int tr = tt / 12, tc = tt - tr * 12;
    const float* W = (mat == 0) ? wq : (mat == 1) ? wk : (mat == 2) ? wv : wo;
    __shared__ u16 sT[64 * 72];
    #pragma unroll
    for (int rr = 0; rr < 4; ++rr) {
        int r = (t >> 4) + rr * 16;
        int cb = (t & 15) * 4;
        float4 v = *(const float4*)&W[(size_t)(tr * 64 + r) * 768 + tc * 64 + cb];
        sT[(cb + 0) * 72 + r] = f2bf(v.x);
        sT[(cb + 1) * 72 + r] = f2bf(v.y);
        sT[(cb + 2) * 72 + r] = f2bf(v.z);
        sT[(cb + 3) * 72 + r] = f2bf(v.w);
    }
    __syncthreads();
    #pragma unroll
    for (int i = 0; i < 2; ++i) {
        int nr = t >> 2;
        int cc = (t & 3) * 16 + i * 8;
        *(uint4*)&WT[(size_t)(mat * 768 + tc * 64 + nr) * 768 + tr * 64 + cc] =
            *(uint4*)&sT[nr * 72 + cc];
    }
    if (tb < 9) {
        int i = tb * 256 + t;
        if (i < 2304)
            bqkv[i] = (i < 768) ? bq[i] : (i < 1536) ? bk[i - 768] : bv[i - 1536];
    }
}

// ---------------- GEMM: BK=64 single-buffer, global_load_lds + XOR swizzle --------
template<int MODE>
__global__ __launch_bounds__(256, 4) void gemm_kernel(
    const u16* __restrict__ A, const u16* __restrict__ WT,
    const float* __restrict__ bias, void* __restrict__ out)
{
    __shared__ u16 sA[128 * 64];
    __shared__ u16 sB[128 * 64];

    const int m0 = blockIdx.x * 128;
    const int n0g = blockIdx.y * 128;
    const int tid = threadIdx.x, lane = tid & 63, wave = tid >> 6;
    const int quad = lane >> 4, l16 = lane & 15;
    const int wm = (wave & 1) * 64, wn = (wave >> 1) * 64;

    f32x4 acc[4][4];
    #pragma unroll
    for (int i = 0; i < 4; ++i)
        #pragma unroll
        for (int j = 0; j < 4; ++j)
            #pragma unroll
            for (int r = 0; r < 4; ++r)
                acc[i][j][r] = 0.f;

    const int srow = (lane >> 3);

    for (int k0 = 0; k0 < 768; k0 += 64) {
        __syncthreads();
        #pragma unroll
        for (int i = 0; i < 4; ++i) {
            int c = wave * 4 + i;
            int row = c * 8 + srow;
            __builtin_amdgcn_global_load_lds(
                AS1(&A[(size_t)(m0 + row) * 768 + k0 + (((lane & 7) ^ (row & 7)) * 8)]),
                AS3(&sA[c * 512]), 16, 0, 0);
            __builtin_amdgcn_global_load_lds(
                AS1(&WT[(size_t)(n0g + row) * 768 + k0 + (((lane & 7) ^ (row & 7)) * 8)]),
                AS3(&sB[c * 512]), 16, 0, 0);
        }
        __syncthreads();
        #pragma unroll
        for (int s = 0; s < 2; ++s) {
            bf16x8 af[4], bfr[4];
            #pragma unroll
            for (int i = 0; i < 4; ++i) {
                int row = wm + i * 16 + l16;
                af[i] = *(const bf16x8*)&sA[row * 64 + (((s * 4 + quad) ^ (row & 7)) * 8)];
            }
            #pragma unroll
            for (int j = 0; j < 4; ++j) {
                int row = wn + j * 16 + l16;
                bfr[j] = *(const bf16x8*)&sB[row * 64 + (((s * 4 + quad) ^ (row & 7)) * 8)];
            }
            #pragma unroll
            for (int i = 0; i < 4; ++i)
                #pragma unroll
                for (int j = 0; j < 4; ++j)
                    acc[i][j] = __builtin_amdgcn_mfma_f32_16x16x32_bf16(af[i], bfr[j], acc[i][j], 0, 0, 0);
        }
    }

    if (MODE == 0) {
        const int mat = blockIdx.y / 6;
        const int nm0 = n0g - mat * 768;
        const float scale = (mat == 0) ? QSCALE : 1.0f;
        u16* dst = (u16*)out + (size_t)mat * NXQ;
        #pragma unroll
        for (int i = 0; i < 4; ++i) {
            #pragma unroll
            for (int j = 0; j < 4; ++j) {
                int colg = n0g + wn + j * 16 + l16;
                int col = nm0 + wn + j * 16 + l16;
                float bv = bias[colg];
                int h = col >> 6, d = col & 63;
                int row0 = m0 + wm + i * 16 + quad * 4;
                int b = row0 >> 12, s = row0 & 4095;
                if (mat < 2) {
                    #pragma unroll
                    for (int r = 0; r < 4; ++r)
                        dst[(((size_t)(b * 12 + h) * 4096) + s + r) * 64 + d] =
                            f2bf((acc[i][j][r] + bv) * scale);
                } else {
                    ushort4 w;
                    w.x = f2bf(acc[i][j][0] + bv);
                    w.y = f2bf(acc[i][j][1] + bv);
                    w.z = f2bf(acc[i][j][2] + bv);
                    w.w = f2bf(acc[i][j][3] + bv);
                    *(ushort4*)&dst[(((size_t)(b * 12 + h) * 64 + d) * 4096) + s] = w;
                }
            }
        }
    } else {
        #pragma unroll
        for (int i = 0; i < 4; ++i) {
            #pragma unroll
            for (int j = 0; j < 4; ++j) {
                int col = n0g + wn + j * 16 + l16;
                float bv = bias[col];
                #pragma unroll
                for (int r = 0; r < 4; ++r) {
                    int row = m0 + wm + i * 16 + quad * 4 + r;
                    ((float*)out)[(size_t)row * 768 + col] = acc[i][j][r] + bv;
                }
            }
        }
    }
}

// ---------------- flash attention: PV via native 16x16x32 (P LDS round-trip) ------
// Q pre-scaled by QSCALE -> p = exp2(score). Row-sums l via all-ones MFMA A-frag.
__global__ __launch_bounds__(256, 2) void flash_kernel(
    const u16* __restrict__ Q, const u16* __restrict__ K,
    const u16* __restrict__ Vt, u16* __restrict__ O)
{
    const int bh = blockIdx.y;
    const int q0 = blockIdx.x * 128;
    const u16* Qp = Q + (size_t)bh * 4096 * 64;
    const u16* Kp = K + (size_t)bh * 4096 * 64;
    const u16* Vp = Vt + (size_t)bh * 64 * 4096;
    const int tid = threadIdx.x, lane = tid & 63, wave = tid >> 6;
    const int quad = lane >> 4, l16 = lane & 15;

    __shared__ u16 sK[2][64 * 64];    // [key][d], XOR-swizzled chunks
    __shared__ u16 sVT[2][64 * 64];   // [d][key]
    __shared__ u16 sP[4][32 * 72];    // per-wave P^T scratch: [q_local][key], stride 72

    const int qrow = q0 + wave * 32;
    bf16x8 qf[2][2];
    #pragma unroll
    for (int i = 0; i < 2; ++i)
        #pragma unroll
        for (int s = 0; s < 2; ++s)
            qf[i][s] = *(const bf16x8*)&Qp[(size_t)(qrow + i * 16 + l16) * 64 + s * 32 + quad * 8];

    f32x4 oacc[4][2];
    f32x4 lacc[2];
    #pragma unroll
    for (int jd = 0; jd < 4; ++jd)
        #pragma unroll
        for (int i = 0; i < 2; ++i)
            #pragma unroll
            for (int r = 0; r < 4; ++r)
                oacc[jd][i][r] = 0.f;
    #pragma unroll
    for (int i = 0; i < 2; ++i)
        #pragma unroll
        for (int r = 0; r < 4; ++r)
            lacc[i][r] = 0.f;

    bf16x8 ones;   // all-ones 16x16x32 A-operand (lane-invariant)
    #pragma unroll
    for (int r = 0; r < 8; ++r) ones[r] = (__bf16)1.0f;

    u16* sPw = &sP[wave][0];

    const int srow = lane >> 3;
    auto stage = [&](int t, int buf) {
        #pragma unroll
        for (int i = 0; i < 2; ++i) {
            int c = wave * 2 + i;
            int row = c * 8 + srow;
            int kc = ((lane & 7) ^ (row & 7)) * 8;
            __builtin_amdgcn_global_load_lds(
                AS1(&Kp[(size_t)(t * 64 + row) * 64 + kc]),
                AS3(&sK[buf][c * 512]), 16, 0, 0);
            __builtin_amdgcn_global_load_lds(
                AS1(&Vp[(size_t)row * 4096 + t * 64 + kc]),
                AS3(&sVT[buf][c * 512]), 16, 0, 0);
        }
    };

    auto body = [&](int cur) {
        // S^T = K @ Q^T
        f32x4 sacc[4][2];
        #pragma unroll
        for (int m = 0; m < 4; ++m)
            #pragma unroll
            for (int i = 0; i < 2; ++i)
                #pragma unroll
                for (int r = 0; r < 4; ++r)
                    sacc[m][i][r] = 0.f;
        #pragma unroll
        for (int s = 0; s < 2; ++s) {
            bf16x8 ak[4];
            #pragma unroll
            for (int m = 0; m < 4; ++m) {
                int row = m * 16 + l16;
                ak[m] = *(const bf16x8*)&sK[cur][row * 64 + (((s * 4 + quad) ^ (row & 7)) * 8)];
            }
            #pragma unroll
            for (int m = 0; m < 4; ++m)
                #pragma unroll
                for (int i = 0; i < 2; ++i)
                    sacc[m][i] = __builtin_amdgcn_mfma_f32_16x16x32_bf16(ak[m], qf[i][s], sacc[m][i], 0, 0, 0);
        }

        // p = exp2(score); write P^T to per-wave LDS as [q][key] (b64 per (i,kk))
        #pragma unroll
        for (int i = 0; i < 2; ++i) {
            #pragma unroll
            for (int kk = 0; kk < 4; ++kk) {
                s16x4 b;
                b[0] = bfbits(EXP2(sacc[kk][i][0]));
                b[1] = bfbits(EXP2(sacc[kk][i][1]));
                b[2] = bfbits(EXP2(sacc[kk][i][2]));
                b[3] = bfbits(EXP2(sacc[kk][i][3]));
                *(s16x4*)&sPw[(i * 16 + l16) * 72 + kk * 16 + quad * 4] = b;
            }
        }

        // O^T += V^T @ P^T with native K=32; l via ones A-frag
        #pragma unroll
        for (int kb = 0; kb < 2; ++kb) {
            bf16x8 av[4], pb[2];
            #pragma unroll
            for (int jd = 0; jd < 4; ++jd) {
                int row = jd * 16 + l16;
                av[jd] = *(const bf16x8*)&sVT[cur][row * 64 + (((kb * 4 + quad) ^ (row & 7)) * 8)];
            }
            #pragma unroll
            for (int i = 0; i < 2; ++i)
                pb[i] = *(const bf16x8*)&sPw[(i * 16 + l16) * 72 + kb * 32 + quad * 8];
            #pragma unroll
            for (int i = 0; i < 2; ++i) {
                #pragma unroll
                for (int jd = 0; jd < 4; ++jd)
                    oacc[jd][i] = __builtin_amdgcn_mfma_f32_16x16x32_bf16(av[jd], pb[i], oacc[jd][i], 0, 0, 0);
                lacc[i] = __builtin_amdgcn_mfma_f32_16x16x32_bf16(ones, pb[i], lacc[i], 0, 0, 0);
            }
        }
    };

    stage(0, 0);
    for (int t = 0; t < 64; t += 2) {
        __syncthreads();
        stage(t + 1, 1);
        body(0);
        __syncthreads();
        if (t + 2 < 64) stage(t + 2, 0);
        body(1);
    }

    const int b = bh / 12, h = bh - b * 12;
    #pragma unroll
    for (int i = 0; i < 2; ++i) {
        float inv = 1.0f / lacc[i][0];
        int s = qrow + i * 16 + l16;
        #pragma unroll
        for (int jd = 0; jd < 4; ++jd) {
            ushort4 w;
            w.x = f2bf(oacc[jd][i][0] * inv);
            w.y = f2bf(oacc[jd][i][1] * inv);
            w.z = f2bf(oacc[jd][i][2] * inv);
            w.w = f2bf(oacc[jd][i][3] * inv);
            *(ushort4*)&O[((size_t)(b * 4096 + s)) * 768 + h * 64 + jd * 16 + quad * 4] = w;
        }
    }
}

extern "C" void kernel_launch(void* const* d_in, const int* in_sizes, int n_in,
                              void* d_out, int out_size, void* d_ws, size_t ws_size,
                              hipStream_t stream)
{
    (void)in_sizes; (void)n_in; (void)out_size; (void)ws_size;
    const float* x  = (const float*)d_in[0];
    const float* wq = (const float*)d_in[1];
    const float* bq = (const float*)d_in[2];
    const float* wk = (const float*)d_in[3];
    const float* bk = (const float*)d_in[4];
    const float* wv = (const float*)d_in[5];
    const float* bv = (const float*)d_in[6];
    const float* wo = (const float*)d_in[7];
    const float* bo = (const float*)d_in[8];
    float* out = (float*)d_out;

    u16* ws = (u16*)d_ws;
    u16* xbf = ws;                          // 8192*768
    u16* WT  = xbf + (size_t)8192 * 768;    // 3072*768 (WqT|WkT|WvT|WoT)
    u16* Qb  = WT + (size_t)3072 * 768;     // NXQ each
    u16* Kb  = Qb + NXQ;
    u16* Vtb = Kb + NXQ;
    u16* Ob  = Vtb + NXQ;
    float* bqkv = (float*)(Ob + NXQ);       // 2304 fp32

    prep_kernel<<<6720, 256, 0, stream>>>(x, wq, wk, wv, wo, bq, bk, bv, xbf, WT, bqkv);
    gemm_kernel<0><<<dim3(64, 18), 256, 0, stream>>>(xbf, WT, bqkv, Qb);
    flash_kernel<<<dim3(32, 24), 256, 0, stream>>>(Qb, Kb, Vtb, Ob);
    gemm_kernel<1><<<dim3(64, 6), 256, 0, stream>>>(Ob, WT + (size_t)2304 * 768, bo, out);
}